// Round 4
// baseline (4005.778 us; speedup 1.0000x reference)
//
#include <hip/hip_runtime.h>

typedef __attribute__((ext_vector_type(8))) short short8;
typedef __attribute__((ext_vector_type(4))) float f32x4;

// Problem constants
#define S_LEN 256
#define BATCH 128
#define IN_DIM 1024
#define HID 512
#define G4 2048  // 4*HID

#define SENT 0xFFFFFFFFu  // 2x bf16 NaN pattern; h=o*tanh(c) can never be NaN

__device__ __forceinline__ unsigned short f32_bf16(float f) {
  unsigned int u = __float_as_uint(f);
  u = (u + 0x7FFFu + ((u >> 16) & 1u)) >> 16;  // RNE
  return (unsigned short)u;
}
__device__ __forceinline__ float bf16_f32(unsigned short h) {
  return __uint_as_float(((unsigned int)h) << 16);
}
__device__ __forceinline__ float sigm(float x) { return 1.0f / (1.0f + __expf(-x)); }
__device__ __forceinline__ float tanh_fast(float x) {
  return 1.0f - 2.0f / (__expf(2.0f * x) + 1.0f);
}

// ---------------- conversion kernels ----------------
__global__ void cvt_bf16(const float* __restrict__ src, unsigned short* __restrict__ dst, int n) {
  int i = (blockIdx.x * blockDim.x + threadIdx.x) * 4;
  if (i >= n) return;
  float4 v = *(const float4*)(src + i);
  ushort4 o;
  o.x = f32_bf16(v.x); o.y = f32_bf16(v.y); o.z = f32_bf16(v.z); o.w = f32_bf16(v.w);
  *(ushort4*)(dst + i) = o;
}

// bias fuse + h-ring init: slot0 = h(0) = 0 (valid), slots 1..3 = sentinel
__global__ void init_all(const float* __restrict__ b_ih, const float* __restrict__ b_hh,
                         float* __restrict__ bias, unsigned* __restrict__ hring) {
  int i = blockIdx.x * blockDim.x + threadIdx.x;
  if (i < G4) bias[i] = b_ih[i] + b_hh[i];
  const int SLOT = BATCH * HID / 2;  // 32768 uints per slot
  for (int k = i; k < SLOT; k += gridDim.x * blockDim.x) {
    hring[k] = 0u;
    hring[SLOT + k] = SENT;
    hring[2 * SLOT + k] = SENT;
    hring[3 * SLOT + k] = SENT;
  }
}

// ---------------- GEMM: Gx = x_bf16 @ w_ih_bf16^T + bias ----------------
__device__ __forceinline__ void gl_lds16(const void* g, void* l) {
  __builtin_amdgcn_global_load_lds(
      (const __attribute__((address_space(1))) unsigned int*)g,
      (__attribute__((address_space(3))) unsigned int*)l, 16, 0, 0);
}

template <int C_F32>
__global__ __launch_bounds__(256) void gemm_bias(
    const unsigned short* __restrict__ A,   // [32768][1024] bf16
    const unsigned short* __restrict__ Bw,  // [2048][1024] bf16
    const float* __restrict__ bias,         // [2048]
    void* __restrict__ Cout) {              // [32768][2048] fp32 or bf16
  __shared__ __align__(16) unsigned short As[128 * 32];
  __shared__ __align__(16) unsigned short Bs[128 * 32];
  const int tid = threadIdx.x;
  const int w = tid >> 6, l = tid & 63;
  const int wm = w & 1, wn = w >> 1;
  const int nt = blockIdx.x & 15, mt = blockIdx.x >> 4;

  f32x4 acc[4][4];
#pragma unroll
  for (int i = 0; i < 4; i++)
#pragma unroll
    for (int j = 0; j < 4; j++) acc[i][j] = f32x4{0.f, 0.f, 0.f, 0.f};

  for (int k0 = 0; k0 < 1024; k0 += 32) {
    __syncthreads();
#pragma unroll
    for (int jj = 0; jj < 2; jj++) {
      int cid = (w * 2 + jj) * 64 + l;
      int row = cid >> 2, kc = cid & 3;
      const unsigned short* ga = A + (size_t)(mt * 128 + row) * 1024 + k0 + kc * 8;
      gl_lds16(ga, As + (w * 2 + jj) * 512);
      const unsigned short* gb = Bw + (size_t)(nt * 128 + row) * 1024 + k0 + kc * 8;
      gl_lds16(gb, Bs + (w * 2 + jj) * 512);
    }
    __syncthreads();
    short8 a[4], b[4];
#pragma unroll
    for (int i = 0; i < 4; i++)
      a[i] = *(const short8*)&As[(wm * 64 + i * 16 + (l & 15)) * 32 + (l >> 4) * 8];
#pragma unroll
    for (int j = 0; j < 4; j++)
      b[j] = *(const short8*)&Bs[(wn * 64 + j * 16 + (l & 15)) * 32 + (l >> 4) * 8];
#pragma unroll
    for (int i = 0; i < 4; i++)
#pragma unroll
      for (int j = 0; j < 4; j++)
        acc[i][j] = __builtin_amdgcn_mfma_f32_16x16x32_bf16(a[i], b[j], acc[i][j], 0, 0, 0);
  }
#pragma unroll
  for (int j = 0; j < 4; j++) {
    int cg = nt * 128 + wn * 64 + j * 16 + (l & 15);
    float bv = bias[cg];
#pragma unroll
    for (int i = 0; i < 4; i++) {
      int rbase = mt * 128 + wm * 64 + i * 16 + (l >> 4) * 4;
#pragma unroll
      for (int r = 0; r < 4; r++) {
        float v = acc[i][j][r] + bv;
        if (C_F32)
          ((float*)Cout)[(size_t)(rbase + r) * 2048 + cg] = v;
        else
          ((unsigned short*)Cout)[(size_t)(rbase + r) * 2048 + cg] = f32_bf16(v);
      }
    }
  }
}

// ---------------- persistent LSTM recurrence (barrier-free) ----------------
// 8 independent groups (batch tiles m), 16 blocks each; waves fully autonomous.
// h exchanged through a 4-deep LLC ring of sentinel-tagged bf16 pairs:
// the consumer's poll load IS the data load. Producers reset their own
// footprint in slot (t-1)&3; the vmcnt(0) before each h-store (draining the
// previous iteration's resets, normally already complete) orders reset
// visibility ahead of the next h visibility.
__global__ __launch_bounds__(256, 1) void lstm_rec(
    const unsigned short* __restrict__ whh,  // [2048][512] bf16
    const void* __restrict__ gx,             // [256][128][2048] fp32 or bf16 (bias folded)
    int gx_f32,
    unsigned* __restrict__ hring) {          // [4][128][512] bf16 ring
  __shared__ __align__(16) float Gt[16][132];  // wave-column-private: no barrier needed

  const int tid = threadIdx.x;
  const int w = tid >> 6, l = tid & 63;
  const int m = blockIdx.x & 7;   // batch tile / group
  const int s = blockIdx.x >> 3;  // hidden slice (16 slices of 32 cols)

  // ---- preload W_hh fragments into registers (constant over t) ----
  short8 bw[16][2];
#pragma unroll
  for (int u = 0; u < 2; u++) {
    int n = (2 * w + u) * 16 + (l & 15);   // local gate-col n = j*4+g
    int jn = n >> 2, g = n & 3;
    int R = g * 512 + s * 32 + jn;         // global gate row
    const unsigned short* base = whh + (size_t)R * 512 + ((l >> 4) * 8);
#pragma unroll
    for (int kk = 0; kk < 16; kk++) bw[kk][u] = *(const short8*)(base + kk * 32);
  }

  // pointwise ownership: batch b = tid&15, col pair p = tid>>4 (pair = own wave's cols)
  const int b = tid & 15;
  const int p = tid >> 4;            // 0..15; wave w owns p in [4w, 4w+4)
  const int gb = m * 16 + b;         // global batch
  const int colg = s * 32 + 2 * p;   // global hidden col (even)
  float c0 = 0.f, c1 = 0.f;

  const float* gxf = (const float*)gx;
  const unsigned short* gxb = (const unsigned short*)gx;
  const int SLOTW = BATCH * HID / 2;  // uints per ring slot
  unsigned long long* hull = (unsigned long long*)hring;
  const int SLOTQ = BATCH * HID / 4;  // ulls per ring slot

  // consumer A-fragment base: row = l&15, col chunk (l>>4)*8 shorts
  const int arow = m * 16 + (l & 15);
  const int aoff = arow * 128 + (l >> 4) * 2;  // in ulls within slot

  for (int t = 0; t < S_LEN; t++) {
    // ---- gx prefetch (independent; overlaps the poll) ----
    float2 pg[4];
    {
      size_t base = (size_t)(t * BATCH + gb) * G4 + colg;
      if (gx_f32) {
#pragma unroll
        for (int g = 0; g < 4; g++) pg[g] = *(const float2*)(gxf + base + (size_t)g * 512);
      } else {
#pragma unroll
        for (int g = 0; g < 4; g++) {
          unsigned u = *(const unsigned*)(gxb + base + (size_t)g * 512);
          pg[g].x = bf16_f32((unsigned short)(u & 0xFFFFu));
          pg[g].y = bf16_f32((unsigned short)(u >> 16));
        }
      }
    }

    const unsigned long long* src = hull + (size_t)(t & 3) * SLOTQ + aoff;
    asm volatile("" ::: "memory");

    // ---- issue all 32 A-chunk loads (LLC-direct), then validate+MFMA ----
    unsigned long long av[32];
#pragma unroll
    for (int kk = 0; kk < 16; kk++) {
      av[2 * kk] = __hip_atomic_load(src + kk * 8, __ATOMIC_RELAXED, __HIP_MEMORY_SCOPE_AGENT);
      av[2 * kk + 1] =
          __hip_atomic_load(src + kk * 8 + 1, __ATOMIC_RELAXED, __HIP_MEMORY_SCOPE_AGENT);
    }

    f32x4 acc0 = f32x4{0.f, 0.f, 0.f, 0.f};
    f32x4 acc1 = f32x4{0.f, 0.f, 0.f, 0.f};
#pragma unroll
    for (int kk = 0; kk < 16; kk++) {
      unsigned long long v0 = av[2 * kk], v1 = av[2 * kk + 1];
      while ((unsigned)v0 == SENT || (unsigned)(v0 >> 32) == SENT)
        v0 = __hip_atomic_load(src + kk * 8, __ATOMIC_RELAXED, __HIP_MEMORY_SCOPE_AGENT);
      while ((unsigned)v1 == SENT || (unsigned)(v1 >> 32) == SENT)
        v1 = __hip_atomic_load(src + kk * 8 + 1, __ATOMIC_RELAXED, __HIP_MEMORY_SCOPE_AGENT);
      union { unsigned long long q[2]; short8 s8; } ua;
      ua.q[0] = v0; ua.q[1] = v1;
      acc0 = __builtin_amdgcn_mfma_f32_16x16x32_bf16(ua.s8, bw[kk][0], acc0, 0, 0, 0);
      acc1 = __builtin_amdgcn_mfma_f32_16x16x32_bf16(ua.s8, bw[kk][1], acc1, 0, 0, 0);
    }

    // ---- Gt exchange (own-wave columns only; in-wave lgkmcnt suffices) ----
#pragma unroll
    for (int r = 0; r < 4; r++) {
      Gt[(l >> 4) * 4 + r][(2 * w + 0) * 16 + (l & 15)] = acc0[r];
      Gt[(l >> 4) * 4 + r][(2 * w + 1) * 16 + (l & 15)] = acc1[r];
    }

    // ---- pointwise: batch b, cols colg / colg+1 ----
    float4 g0 = *(const float4*)&Gt[b][8 * p];
    float4 g1 = *(const float4*)&Gt[b][8 * p + 4];
    float i0 = sigm(g0.x + pg[0].x), f0 = sigm(g0.y + pg[1].x);
    float gg0 = tanh_fast(g0.z + pg[2].x), o0 = sigm(g0.w + pg[3].x);
    c0 = f0 * c0 + i0 * gg0;
    float h0 = o0 * tanh_fast(c0);
    float i1 = sigm(g1.x + pg[0].y), f1 = sigm(g1.y + pg[1].y);
    float gg1 = tanh_fast(g1.z + pg[2].y), o1 = sigm(g1.w + pg[3].y);
    c1 = f1 * c1 + i1 * gg1;
    float h1 = o1 * tanh_fast(c1);
    unsigned hp = (unsigned)f32_bf16(h0) | ((unsigned)f32_bf16(h1) << 16);

    // ---- order: prev-iter resets drained (usually free) -> store h -> reset old slot ----
    asm volatile("s_waitcnt vmcnt(0)" ::: "memory");
    const int myoff = gb * 256 + s * 16 + p;
    __hip_atomic_store(&hring[(size_t)((t + 1) & 3) * SLOTW + myoff], hp, __ATOMIC_RELAXED,
                       __HIP_MEMORY_SCOPE_AGENT);
    __hip_atomic_store(&hring[(size_t)((t + 3) & 3) * SLOTW + myoff], SENT, __ATOMIC_RELAXED,
                       __HIP_MEMORY_SCOPE_AGENT);
    asm volatile("" ::: "memory");
  }
  // final h(256) lands in slot (255+1)&3 == 0
}

// ---------------- final reduction: sum over h [128][512] (ring slot 0) ----------------
__global__ void reduce_sum(const unsigned short* __restrict__ h, float* __restrict__ out) {
  __shared__ float red[256];
  int tid = threadIdx.x;
  float s = 0.f;
  for (int i = tid * 8; i < BATCH * HID; i += 256 * 8) {
    uint4 v = *(const uint4*)(h + i);
    unsigned int q[4] = {v.x, v.y, v.z, v.w};
#pragma unroll
    for (int k = 0; k < 4; k++) {
      s += bf16_f32((unsigned short)(q[k] & 0xFFFFu));
      s += bf16_f32((unsigned short)(q[k] >> 16));
    }
  }
  red[tid] = s;
  __syncthreads();
  for (int off = 128; off > 0; off >>= 1) {
    if (tid < off) red[tid] += red[tid + off];
    __syncthreads();
  }
  if (tid == 0) out[0] = red[0];
}

// ---------------- launch ----------------
extern "C" void kernel_launch(void* const* d_in, const int* in_sizes, int n_in,
                              void* d_out, int out_size, void* d_ws, size_t ws_size,
                              hipStream_t stream) {
  const float* x = (const float*)d_in[0];     // [256][128][1024]
  const float* w_ih = (const float*)d_in[1];  // [2048][1024]
  const float* w_hh = (const float*)d_in[2];  // [2048][512]
  const float* b_ih = (const float*)d_in[3];  // [2048]
  const float* b_hh = (const float*)d_in[4];  // [2048]

  char* ws = (char*)d_ws;
  unsigned short* x_bf = (unsigned short*)(ws);                 // 67,108,864 B
  unsigned short* wih_bf = (unsigned short*)(ws + 67108864);    //  4,194,304 B
  unsigned short* whh_bf = (unsigned short*)(ws + 71303168);    //  2,097,152 B
  float* bias = (float*)(ws + 73400320);                        //      8,192 B
  unsigned* hring = (unsigned*)(ws + 73408512);                 //    524,288 B (4 slots)
  void* gx = (void*)(ws + 73932800);                            // Gx

  const size_t need_f32 = 73932800ull + (size_t)S_LEN * BATCH * G4 * 4;  // ~327 MB
  int gx_f32 = (ws_size >= need_f32) ? 1 : 0;

  // conversions + ring/bias init
  cvt_bf16<<<(33554432 / 4 + 255) / 256, 256, 0, stream>>>(x, x_bf, 33554432);
  cvt_bf16<<<(2097152 / 4 + 255) / 256, 256, 0, stream>>>(w_ih, wih_bf, 2097152);
  cvt_bf16<<<(1048576 / 4 + 255) / 256, 256, 0, stream>>>(w_hh, whh_bf, 1048576);
  init_all<<<32, 256, 0, stream>>>(b_ih, b_hh, bias, hring);

  // big input GEMM (bias folded)
  if (gx_f32)
    gemm_bias<1><<<4096, 256, 0, stream>>>(x_bf, wih_bf, bias, gx);
  else
    gemm_bias<0><<<4096, 256, 0, stream>>>(x_bf, wih_bf, bias, gx);

  // persistent recurrence (co-residency via cooperative launch; no cg sync used)
  void* args[] = {(void*)&whh_bf, (void*)&gx, (void*)&gx_f32, (void*)&hring};
  hipLaunchCooperativeKernel((const void*)lstm_rec, dim3(128), dim3(256), args, 0, stream);

  // scalar output from ring slot 0
  reduce_sum<<<1, 256, 0, stream>>>((const unsigned short*)hring, (float*)d_out);
}

// Round 5
// 2039.747 us; speedup vs baseline: 1.9639x; 1.9639x over previous
//
#include <hip/hip_runtime.h>

typedef __attribute__((ext_vector_type(8))) short short8;
typedef __attribute__((ext_vector_type(4))) float f32x4;

// Problem constants
#define S_LEN 256
#define BATCH 128
#define IN_DIM 1024
#define HID 512
#define G4 2048  // 4*HID

__device__ __forceinline__ unsigned short f32_bf16(float f) {
  unsigned int u = __float_as_uint(f);
  u = (u + 0x7FFFu + ((u >> 16) & 1u)) >> 16;  // RNE
  return (unsigned short)u;
}
__device__ __forceinline__ float bf16_f32(unsigned short h) {
  return __uint_as_float(((unsigned int)h) << 16);
}
__device__ __forceinline__ float sigm(float x) { return 1.0f / (1.0f + __expf(-x)); }
__device__ __forceinline__ float tanh_fast(float x) {
  return 1.0f - 2.0f / (__expf(2.0f * x) + 1.0f);
}

// ---------------- conversion kernels ----------------
__global__ void cvt_bf16(const float* __restrict__ src, unsigned short* __restrict__ dst, int n) {
  int i = (blockIdx.x * blockDim.x + threadIdx.x) * 4;
  if (i >= n) return;
  float4 v = *(const float4*)(src + i);
  ushort4 o;
  o.x = f32_bf16(v.x); o.y = f32_bf16(v.y); o.z = f32_bf16(v.z); o.w = f32_bf16(v.w);
  *(ushort4*)(dst + i) = o;
}

// bias fuse + zero h slot0 (h(0)=0) + zero per-wave flags
__global__ void init_all(const float* __restrict__ b_ih, const float* __restrict__ b_hh,
                         float* __restrict__ bias, unsigned* __restrict__ hbuf,
                         unsigned* __restrict__ flags) {
  int i = blockIdx.x * blockDim.x + threadIdx.x;
  if (i < G4) bias[i] = b_ih[i] + b_hh[i];
  if (i < 8192) flags[i] = 0u;
  const int SLOT = BATCH * HID / 2;  // 32768 uints per h slot
  for (int k = i; k < SLOT; k += gridDim.x * blockDim.x) hbuf[k] = 0u;
}

// ---------------- GEMM: Gx = x_bf16 @ w_ih_bf16^T + bias ----------------
__device__ __forceinline__ void gl_lds16(const void* g, void* l) {
  __builtin_amdgcn_global_load_lds(
      (const __attribute__((address_space(1))) unsigned int*)g,
      (__attribute__((address_space(3))) unsigned int*)l, 16, 0, 0);
}

template <int C_F32>
__global__ __launch_bounds__(256) void gemm_bias(
    const unsigned short* __restrict__ A,   // [32768][1024] bf16
    const unsigned short* __restrict__ Bw,  // [2048][1024] bf16
    const float* __restrict__ bias,         // [2048]
    void* __restrict__ Cout) {              // [32768][2048] fp32 or bf16
  __shared__ __align__(16) unsigned short As[128 * 32];
  __shared__ __align__(16) unsigned short Bs[128 * 32];
  const int tid = threadIdx.x;
  const int w = tid >> 6, l = tid & 63;
  const int wm = w & 1, wn = w >> 1;
  const int nt = blockIdx.x & 15, mt = blockIdx.x >> 4;

  f32x4 acc[4][4];
#pragma unroll
  for (int i = 0; i < 4; i++)
#pragma unroll
    for (int j = 0; j < 4; j++) acc[i][j] = f32x4{0.f, 0.f, 0.f, 0.f};

  for (int k0 = 0; k0 < 1024; k0 += 32) {
    __syncthreads();
#pragma unroll
    for (int jj = 0; jj < 2; jj++) {
      int cid = (w * 2 + jj) * 64 + l;
      int row = cid >> 2, kc = cid & 3;
      const unsigned short* ga = A + (size_t)(mt * 128 + row) * 1024 + k0 + kc * 8;
      gl_lds16(ga, As + (w * 2 + jj) * 512);
      const unsigned short* gb = Bw + (size_t)(nt * 128 + row) * 1024 + k0 + kc * 8;
      gl_lds16(gb, Bs + (w * 2 + jj) * 512);
    }
    __syncthreads();
    short8 a[4], b[4];
#pragma unroll
    for (int i = 0; i < 4; i++)
      a[i] = *(const short8*)&As[(wm * 64 + i * 16 + (l & 15)) * 32 + (l >> 4) * 8];
#pragma unroll
    for (int j = 0; j < 4; j++)
      b[j] = *(const short8*)&Bs[(wn * 64 + j * 16 + (l & 15)) * 32 + (l >> 4) * 8];
#pragma unroll
    for (int i = 0; i < 4; i++)
#pragma unroll
      for (int j = 0; j < 4; j++)
        acc[i][j] = __builtin_amdgcn_mfma_f32_16x16x32_bf16(a[i], b[j], acc[i][j], 0, 0, 0);
  }
#pragma unroll
  for (int j = 0; j < 4; j++) {
    int cg = nt * 128 + wn * 64 + j * 16 + (l & 15);
    float bv = bias[cg];
#pragma unroll
    for (int i = 0; i < 4; i++) {
      int rbase = mt * 128 + wm * 64 + i * 16 + (l >> 4) * 4;
#pragma unroll
      for (int r = 0; r < 4; r++) {
        float v = acc[i][j][r] + bv;
        if (C_F32)
          ((float*)Cout)[(size_t)(rbase + r) * 2048 + cg] = v;
        else
          ((unsigned short*)Cout)[(size_t)(rbase + r) * 2048 + cg] = f32_bf16(v);
      }
    }
  }
}

// ---------------- persistent LSTM recurrence (per-wave flags, no barriers) ----------------
// 8 independent groups (batch tiles m), 16 blocks x 4 waves each = 64 waves/group.
// Producer wave: store h pairs (4B atomics) -> vmcnt(0) -> store own flag = t+1.
// Consumer wave: poll all 64 group flags in ONE load (lane l -> flag line l),
// __all(flag >= t), then bulk-load A-fragments direct from LLC into registers.
// Waves fully autonomous: zero __syncthreads in the whole loop.
__global__ __launch_bounds__(256, 1) void lstm_rec(
    const unsigned short* __restrict__ whh,  // [2048][512] bf16
    const void* __restrict__ gx,             // [256][128][2048] fp32 or bf16 (bias folded)
    int gx_f32,
    unsigned* __restrict__ hbuf,             // [2][128][512] bf16 (as uints: pairs)
    unsigned* __restrict__ flags) {          // [8 groups][64 waves][16] uints (64B lines)
  __shared__ __align__(16) float Gt[16][132];  // wave-column-private

  const int tid = threadIdx.x;
  const int w = tid >> 6, l = tid & 63;
  const int m = blockIdx.x & 7;   // batch tile / group
  const int s = blockIdx.x >> 3;  // hidden slice (16 slices of 32 cols)

  // ---- preload W_hh fragments (constant over t) ----
  short8 bw[16][2];
#pragma unroll
  for (int u = 0; u < 2; u++) {
    int n = (2 * w + u) * 16 + (l & 15);   // local gate-col n = j*4+g
    int jn = n >> 2, g = n & 3;
    int R = g * 512 + s * 32 + jn;         // global gate row
    const unsigned short* base = whh + (size_t)R * 512 + ((l >> 4) * 8);
#pragma unroll
    for (int kk = 0; kk < 16; kk++) bw[kk][u] = *(const short8*)(base + kk * 32);
  }

  // pointwise ownership: batch b = l&15, col pair p = 4w + (l>>4) (own wave's Gt cols)
  const int b = l & 15;
  const int p = 4 * w + (l >> 4);
  const int gb = m * 16 + b;
  const int colg = s * 32 + 2 * p;
  float c0 = 0.f, c1 = 0.f;

  const float* gxf = (const float*)gx;
  const unsigned short* gxb = (const unsigned short*)gx;
  const int SLOTW = BATCH * HID / 2;  // uints per h slot
  const unsigned long long* hull = (const unsigned long long*)hbuf;
  const int SLOTQ = BATCH * HID / 4;  // ulls per h slot

  // consumer A-fragment base: row = l&15, col chunk (l>>4)*8 shorts
  const int aoff = (m * 16 + (l & 15)) * 128 + (l >> 4) * 2;  // ulls within slot

  // flag addresses
  unsigned* myflag = &flags[(m * 64 + s * 4 + w) * 16];
  const unsigned* pollflag = &flags[(m * 64 + l) * 16];

  for (int t = 0; t < S_LEN; t++) {
    // ---- gx prefetch (independent of h; overlaps poll) ----
    float2 pg[4];
    {
      size_t base = (size_t)(t * BATCH + gb) * G4 + colg;
      if (gx_f32) {
#pragma unroll
        for (int g = 0; g < 4; g++) pg[g] = *(const float2*)(gxf + base + (size_t)g * 512);
      } else {
#pragma unroll
        for (int g = 0; g < 4; g++) {
          unsigned u = *(const unsigned*)(gxb + base + (size_t)g * 512);
          pg[g].x = bf16_f32((unsigned short)(u & 0xFFFFu));
          pg[g].y = bf16_f32((unsigned short)(u >> 16));
        }
      }
    }

    // ---- wait: all 64 producer waves of this group at step t (one load / RTT) ----
    if (t > 0) {
      unsigned v;
      do {
        v = __hip_atomic_load(pollflag, __ATOMIC_RELAXED, __HIP_MEMORY_SCOPE_AGENT);
      } while (!__all(v >= (unsigned)t));
      asm volatile("" ::: "memory");
    }

    // ---- bulk-load A-fragments (LLC-direct) into registers ----
    const unsigned long long* src = hull + (size_t)(t & 1) * SLOTQ + aoff;
    unsigned long long av[32];
#pragma unroll
    for (int kk = 0; kk < 16; kk++) {
      av[2 * kk] = __hip_atomic_load(src + kk * 8, __ATOMIC_RELAXED, __HIP_MEMORY_SCOPE_AGENT);
      av[2 * kk + 1] =
          __hip_atomic_load(src + kk * 8 + 1, __ATOMIC_RELAXED, __HIP_MEMORY_SCOPE_AGENT);
    }

    f32x4 acc0 = f32x4{0.f, 0.f, 0.f, 0.f};
    f32x4 acc1 = f32x4{0.f, 0.f, 0.f, 0.f};
#pragma unroll
    for (int kk = 0; kk < 16; kk++) {
      union { unsigned long long q[2]; short8 s8; } ua;
      ua.q[0] = av[2 * kk]; ua.q[1] = av[2 * kk + 1];
      acc0 = __builtin_amdgcn_mfma_f32_16x16x32_bf16(ua.s8, bw[kk][0], acc0, 0, 0, 0);
      acc1 = __builtin_amdgcn_mfma_f32_16x16x32_bf16(ua.s8, bw[kk][1], acc1, 0, 0, 0);
    }

    // ---- Gt exchange (own-wave columns only; in-wave lgkmcnt suffices) ----
#pragma unroll
    for (int r = 0; r < 4; r++) {
      Gt[(l >> 4) * 4 + r][(2 * w + 0) * 16 + (l & 15)] = acc0[r];
      Gt[(l >> 4) * 4 + r][(2 * w + 1) * 16 + (l & 15)] = acc1[r];
    }

    // ---- pointwise: batch b, cols colg / colg+1 ----
    float4 g0 = *(const float4*)&Gt[b][8 * p];
    float4 g1 = *(const float4*)&Gt[b][8 * p + 4];
    float i0 = sigm(g0.x + pg[0].x), f0 = sigm(g0.y + pg[1].x);
    float gg0 = tanh_fast(g0.z + pg[2].x), o0 = sigm(g0.w + pg[3].x);
    c0 = f0 * c0 + i0 * gg0;
    float h0 = o0 * tanh_fast(c0);
    float i1 = sigm(g1.x + pg[0].y), f1 = sigm(g1.y + pg[1].y);
    float gg1 = tanh_fast(g1.z + pg[2].y), o1 = sigm(g1.w + pg[3].y);
    c1 = f1 * c1 + i1 * gg1;
    float h1 = o1 * tanh_fast(c1);
    unsigned hp = (unsigned)f32_bf16(h0) | ((unsigned)f32_bf16(h1) << 16);

    // ---- store h(t+1), drain, raise own wave flag ----
    __hip_atomic_store(&hbuf[(size_t)((t + 1) & 1) * SLOTW + gb * 256 + s * 16 + p], hp,
                       __ATOMIC_RELAXED, __HIP_MEMORY_SCOPE_AGENT);
    if (t + 1 < S_LEN) {
      asm volatile("s_waitcnt vmcnt(0)" ::: "memory");  // h stores ack'd at LLC
      if (l == 0)
        __hip_atomic_store(myflag, (unsigned)(t + 1), __ATOMIC_RELAXED,
                           __HIP_MEMORY_SCOPE_AGENT);
    }
  }
  // final h(256) lands in slot 0
}

// ---------------- final reduction: sum over h [128][512] (slot 0) ----------------
__global__ void reduce_sum(const unsigned short* __restrict__ h, float* __restrict__ out) {
  __shared__ float red[256];
  int tid = threadIdx.x;
  float s = 0.f;
  for (int i = tid * 8; i < BATCH * HID; i += 256 * 8) {
    uint4 v = *(const uint4*)(h + i);
    unsigned int q[4] = {v.x, v.y, v.z, v.w};
#pragma unroll
    for (int k = 0; k < 4; k++) {
      s += bf16_f32((unsigned short)(q[k] & 0xFFFFu));
      s += bf16_f32((unsigned short)(q[k] >> 16));
    }
  }
  red[tid] = s;
  __syncthreads();
  for (int off = 128; off > 0; off >>= 1) {
    if (tid < off) red[tid] += red[tid + off];
    __syncthreads();
  }
  if (tid == 0) out[0] = red[0];
}

// ---------------- launch ----------------
extern "C" void kernel_launch(void* const* d_in, const int* in_sizes, int n_in,
                              void* d_out, int out_size, void* d_ws, size_t ws_size,
                              hipStream_t stream) {
  const float* x = (const float*)d_in[0];     // [256][128][1024]
  const float* w_ih = (const float*)d_in[1];  // [2048][1024]
  const float* w_hh = (const float*)d_in[2];  // [2048][512]
  const float* b_ih = (const float*)d_in[3];  // [2048]
  const float* b_hh = (const float*)d_in[4];  // [2048]

  char* ws = (char*)d_ws;
  unsigned short* x_bf = (unsigned short*)(ws);                 // 67,108,864 B
  unsigned short* wih_bf = (unsigned short*)(ws + 67108864);    //  4,194,304 B
  unsigned short* whh_bf = (unsigned short*)(ws + 71303168);    //  2,097,152 B
  float* bias = (float*)(ws + 73400320);                        //      8,192 B
  unsigned* hbuf = (unsigned*)(ws + 73408512);                  //    262,144 B (2 slots)
  unsigned* flags = (unsigned*)(ws + 73670656);                 //     32,768 B
  void* gx = (void*)(ws + 73703424);                            // Gx

  const size_t need_f32 = 73703424ull + (size_t)S_LEN * BATCH * G4 * 4;  // ~342 MB
  int gx_f32 = (ws_size >= need_f32) ? 1 : 0;

  // conversions + init
  cvt_bf16<<<(33554432 / 4 + 255) / 256, 256, 0, stream>>>(x, x_bf, 33554432);
  cvt_bf16<<<(2097152 / 4 + 255) / 256, 256, 0, stream>>>(w_ih, wih_bf, 2097152);
  cvt_bf16<<<(1048576 / 4 + 255) / 256, 256, 0, stream>>>(w_hh, whh_bf, 1048576);
  init_all<<<32, 256, 0, stream>>>(b_ih, b_hh, bias, hbuf, flags);

  // big input GEMM (bias folded)
  if (gx_f32)
    gemm_bias<1><<<4096, 256, 0, stream>>>(x_bf, wih_bf, bias, gx);
  else
    gemm_bias<0><<<4096, 256, 0, stream>>>(x_bf, wih_bf, bias, gx);

  // persistent recurrence (co-residency via cooperative launch; custom flag sync)
  void* args[] = {(void*)&whh_bf, (void*)&gx, (void*)&gx_f32, (void*)&hbuf, (void*)&flags};
  hipLaunchCooperativeKernel((const void*)lstm_rec, dim3(128), dim3(256), args, 0, stream);

  // scalar output from slot 0
  reduce_sum<<<1, 256, 0, stream>>>((const unsigned short*)hbuf, (float*)d_out);
}

// Round 6
// 1557.033 us; speedup vs baseline: 2.5727x; 1.3100x over previous
//
#include <hip/hip_runtime.h>

typedef __attribute__((ext_vector_type(8))) short short8;
typedef __attribute__((ext_vector_type(4))) float f32x4;

// Problem constants
#define S_LEN 256
#define BATCH 128
#define IN_DIM 1024
#define HID 512
#define G4 2048  // 4*HID

#define SENT 0xFFFFFFFFu  // 2x bf16 NaN; h=o*tanh(c) can never be NaN

__device__ __forceinline__ unsigned short f32_bf16(float f) {
  unsigned int u = __float_as_uint(f);
  u = (u + 0x7FFFu + ((u >> 16) & 1u)) >> 16;  // RNE
  return (unsigned short)u;
}
__device__ __forceinline__ float bf16_f32(unsigned short h) {
  return __uint_as_float(((unsigned int)h) << 16);
}
__device__ __forceinline__ float sigm(float x) { return 1.0f / (1.0f + __expf(-x)); }
__device__ __forceinline__ float tanh_fast(float x) {
  return 1.0f - 2.0f / (__expf(2.0f * x) + 1.0f);
}

// ---------------- conversion kernels ----------------
__global__ void cvt_bf16(const float* __restrict__ src, unsigned short* __restrict__ dst, int n) {
  int i = (blockIdx.x * blockDim.x + threadIdx.x) * 4;
  if (i >= n) return;
  float4 v = *(const float4*)(src + i);
  ushort4 o;
  o.x = f32_bf16(v.x); o.y = f32_bf16(v.y); o.z = f32_bf16(v.z); o.w = f32_bf16(v.w);
  *(ushort4*)(dst + i) = o;
}

// bias fuse + ring init: slot0 = h(0) = 0 (valid), slots 1..3 = sentinel
__global__ void init_all(const float* __restrict__ b_ih, const float* __restrict__ b_hh,
                         float* __restrict__ bias, unsigned* __restrict__ hring) {
  int i = blockIdx.x * blockDim.x + threadIdx.x;
  if (i < G4) bias[i] = b_ih[i] + b_hh[i];
  const int SLOT = BATCH * HID / 2;  // 32768 uints per slot
  for (int k = i; k < SLOT; k += gridDim.x * blockDim.x) {
    hring[k] = 0u;
    hring[SLOT + k] = SENT;
    hring[2 * SLOT + k] = SENT;
    hring[3 * SLOT + k] = SENT;
  }
}

// ---------------- GEMM: Gx = x_bf16 @ w_ih_bf16^T + bias ----------------
__device__ __forceinline__ void gl_lds16(const void* g, void* l) {
  __builtin_amdgcn_global_load_lds(
      (const __attribute__((address_space(1))) unsigned int*)g,
      (__attribute__((address_space(3))) unsigned int*)l, 16, 0, 0);
}

template <int C_F32>
__global__ __launch_bounds__(256) void gemm_bias(
    const unsigned short* __restrict__ A,   // [32768][1024] bf16
    const unsigned short* __restrict__ Bw,  // [2048][1024] bf16
    const float* __restrict__ bias,         // [2048]
    void* __restrict__ Cout) {              // [32768][2048] fp32 or bf16
  __shared__ __align__(16) unsigned short As[128 * 32];
  __shared__ __align__(16) unsigned short Bs[128 * 32];
  const int tid = threadIdx.x;
  const int w = tid >> 6, l = tid & 63;
  const int wm = w & 1, wn = w >> 1;
  const int nt = blockIdx.x & 15, mt = blockIdx.x >> 4;

  f32x4 acc[4][4];
#pragma unroll
  for (int i = 0; i < 4; i++)
#pragma unroll
    for (int j = 0; j < 4; j++) acc[i][j] = f32x4{0.f, 0.f, 0.f, 0.f};

  for (int k0 = 0; k0 < 1024; k0 += 32) {
    __syncthreads();
#pragma unroll
    for (int jj = 0; jj < 2; jj++) {
      int cid = (w * 2 + jj) * 64 + l;
      int row = cid >> 2, kc = cid & 3;
      const unsigned short* ga = A + (size_t)(mt * 128 + row) * 1024 + k0 + kc * 8;
      gl_lds16(ga, As + (w * 2 + jj) * 512);
      const unsigned short* gb = Bw + (size_t)(nt * 128 + row) * 1024 + k0 + kc * 8;
      gl_lds16(gb, Bs + (w * 2 + jj) * 512);
    }
    __syncthreads();
    short8 a[4], b[4];
#pragma unroll
    for (int i = 0; i < 4; i++)
      a[i] = *(const short8*)&As[(wm * 64 + i * 16 + (l & 15)) * 32 + (l >> 4) * 8];
#pragma unroll
    for (int j = 0; j < 4; j++)
      b[j] = *(const short8*)&Bs[(wn * 64 + j * 16 + (l & 15)) * 32 + (l >> 4) * 8];
#pragma unroll
    for (int i = 0; i < 4; i++)
#pragma unroll
      for (int j = 0; j < 4; j++)
        acc[i][j] = __builtin_amdgcn_mfma_f32_16x16x32_bf16(a[i], b[j], acc[i][j], 0, 0, 0);
  }
#pragma unroll
  for (int j = 0; j < 4; j++) {
    int cg = nt * 128 + wn * 64 + j * 16 + (l & 15);
    float bv = bias[cg];
#pragma unroll
    for (int i = 0; i < 4; i++) {
      int rbase = mt * 128 + wm * 64 + i * 16 + (l >> 4) * 4;
#pragma unroll
      for (int r = 0; r < 4; r++) {
        float v = acc[i][j][r] + bv;
        if (C_F32)
          ((float*)Cout)[(size_t)(rbase + r) * 2048 + cg] = v;
        else
          ((unsigned short*)Cout)[(size_t)(rbase + r) * 2048 + cg] = f32_bf16(v);
      }
    }
  }
}

// ---------------- persistent LSTM recurrence ----------------
// 8 independent groups (batch tiles m), 16 blocks each. h exchanged via a
// 4-deep sentinel-tagged LLC ring. Consumer: BULK 16KB staged load into LDS,
// block-wide sentinel vote (__syncthreads_and), retry whole round until clean.
// The data load IS the sync: no flags, no counters, no store-drain on the
// producer path. Producers reset their own footprint in slot (t-1)&3; the
// vmcnt(0) before each h-store drains the prior iteration's resets (R4-proven).
// Hs double-buffered -> exactly one block barrier (the vote) per step.
__global__ __launch_bounds__(256, 1) void lstm_rec(
    const unsigned short* __restrict__ whh,  // [2048][512] bf16
    const void* __restrict__ gx,             // [256][128][2048] fp32 or bf16 (bias folded)
    int gx_f32,
    unsigned* __restrict__ hring) {          // [4][128][512] bf16 ring
  __shared__ __align__(16) unsigned short Hs[2][16][520];  // double-buffered h tile
  __shared__ __align__(16) float Gt[16][132];              // wave-column-private

  const int tid = threadIdx.x;
  const int w = tid >> 6, l = tid & 63;
  const int m = blockIdx.x & 7;   // batch tile / group (round-robin XCD)
  const int s = blockIdx.x >> 3;  // hidden slice (16 slices of 32 cols)

  // ---- preload W_hh fragments (constant over t) ----
  short8 bw[16][2];
#pragma unroll
  for (int u = 0; u < 2; u++) {
    int n = (2 * w + u) * 16 + (l & 15);   // local gate-col n = j*4+g
    int jn = n >> 2, g = n & 3;
    int R = g * 512 + s * 32 + jn;         // global gate row
    const unsigned short* base = whh + (size_t)R * 512 + ((l >> 4) * 8);
#pragma unroll
    for (int kk = 0; kk < 16; kk++) bw[kk][u] = *(const short8*)(base + kk * 32);
  }

  // pointwise ownership: batch b = l&15, col pair p = 4w + (l>>4) (wave-aligned)
  const int b = l & 15;
  const int p = 4 * w + (l >> 4);
  const int gb = m * 16 + b;
  const int colg = s * 32 + 2 * p;
  float c0 = 0.f, c1 = 0.f;

  const float* gxf = (const float*)gx;
  const unsigned short* gxb = (const unsigned short*)gx;
  const int SLOTW = BATCH * HID / 2;  // uints per slot
  const unsigned long long* hull = (const unsigned long long*)hring;
  const int SLOTQ = BATCH * HID / 4;  // ulls per slot

  // staging pattern: thread stages 8 qwords (64B) of the [16][512] tile
  // chunk c = it*256+tid; row = c>>7, kc = c&127
  const int srow = tid >> 7;          // base row pair selector (rows advance by 2 per it)
  (void)srow;

  for (int t = 0; t < S_LEN; t++) {
    // ---- gx prefetch (independent of h; overlaps the staging wait) ----
    float2 pg[4];
    {
      size_t base = (size_t)(t * BATCH + gb) * G4 + colg;
      if (gx_f32) {
#pragma unroll
        for (int g = 0; g < 4; g++) pg[g] = *(const float2*)(gxf + base + (size_t)g * 512);
      } else {
#pragma unroll
        for (int g = 0; g < 4; g++) {
          unsigned u = *(const unsigned*)(gxb + base + (size_t)g * 512);
          pg[g].x = bf16_f32((unsigned short)(u & 0xFFFFu));
          pg[g].y = bf16_f32((unsigned short)(u >> 16));
        }
      }
    }

    // ---- bulk staged load of h(t) tile + sentinel vote (retry whole round) ----
    const unsigned long long* src = hull + (size_t)(t & 3) * SLOTQ;
    const int buf = t & 1;
    int ok;
    do {
      unsigned long long v[8];
#pragma unroll
      for (int it = 0; it < 8; it++) {
        int c = it * 256 + tid;  // 2048 chunks of 8B
        int row = c >> 7, kc = c & 127;
        v[it] = __hip_atomic_load(&src[(size_t)(m * 16 + row) * 128 + kc], __ATOMIC_RELAXED,
                                  __HIP_MEMORY_SCOPE_AGENT);
      }
      ok = 1;
#pragma unroll
      for (int it = 0; it < 8; it++) {
        ok &= ((unsigned)v[it] != SENT);
        ok &= ((unsigned)(v[it] >> 32) != SENT);
      }
#pragma unroll
      for (int it = 0; it < 8; it++) {
        int c = it * 256 + tid;
        int row = c >> 7, kc = c & 127;
        *(unsigned long long*)&Hs[buf][row][kc * 4] = v[it];
      }
    } while (!__syncthreads_and(ok));

    // ---- gates tile via MFMA (LDS A-fragments, register B) ----
    f32x4 acc0 = f32x4{0.f, 0.f, 0.f, 0.f};
    f32x4 acc1 = f32x4{0.f, 0.f, 0.f, 0.f};
#pragma unroll
    for (int kk = 0; kk < 16; kk++) {
      short8 a = *(const short8*)&Hs[buf][l & 15][kk * 32 + (l >> 4) * 8];
      acc0 = __builtin_amdgcn_mfma_f32_16x16x32_bf16(a, bw[kk][0], acc0, 0, 0, 0);
      acc1 = __builtin_amdgcn_mfma_f32_16x16x32_bf16(a, bw[kk][1], acc1, 0, 0, 0);
    }

    // ---- Gt exchange (own-wave columns only; in-wave lgkmcnt suffices) ----
#pragma unroll
    for (int r = 0; r < 4; r++) {
      Gt[(l >> 4) * 4 + r][(2 * w + 0) * 16 + (l & 15)] = acc0[r];
      Gt[(l >> 4) * 4 + r][(2 * w + 1) * 16 + (l & 15)] = acc1[r];
    }

    // ---- pointwise: batch b, cols colg / colg+1 ----
    float4 g0 = *(const float4*)&Gt[b][8 * p];
    float4 g1 = *(const float4*)&Gt[b][8 * p + 4];
    float i0 = sigm(g0.x + pg[0].x), f0 = sigm(g0.y + pg[1].x);
    float gg0 = tanh_fast(g0.z + pg[2].x), o0 = sigm(g0.w + pg[3].x);
    c0 = f0 * c0 + i0 * gg0;
    float h0 = o0 * tanh_fast(c0);
    float i1 = sigm(g1.x + pg[0].y), f1 = sigm(g1.y + pg[1].y);
    float gg1 = tanh_fast(g1.z + pg[2].y), o1 = sigm(g1.w + pg[3].y);
    c1 = f1 * c1 + i1 * gg1;
    float h1 = o1 * tanh_fast(c1);
    unsigned hp = (unsigned)f32_bf16(h0) | ((unsigned)f32_bf16(h1) << 16);

    // ---- order: prev resets drained -> store h(t+1) -> reset slot (t-1) ----
    asm volatile("s_waitcnt vmcnt(0)" ::: "memory");
    const int myoff = gb * 256 + s * 16 + p;
    __hip_atomic_store(&hring[(size_t)((t + 1) & 3) * SLOTW + myoff], hp, __ATOMIC_RELAXED,
                       __HIP_MEMORY_SCOPE_AGENT);
    __hip_atomic_store(&hring[(size_t)((t + 3) & 3) * SLOTW + myoff], SENT, __ATOMIC_RELAXED,
                       __HIP_MEMORY_SCOPE_AGENT);
  }
  // final h(256) lands in slot (255+1)&3 == 0
}

// ---------------- final reduction: sum over h [128][512] (ring slot 0) ----------------
__global__ void reduce_sum(const unsigned short* __restrict__ h, float* __restrict__ out) {
  __shared__ float red[256];
  int tid = threadIdx.x;
  float s = 0.f;
  for (int i = tid * 8; i < BATCH * HID; i += 256 * 8) {
    uint4 v = *(const uint4*)(h + i);
    unsigned int q[4] = {v.x, v.y, v.z, v.w};
#pragma unroll
    for (int k = 0; k < 4; k++) {
      s += bf16_f32((unsigned short)(q[k] & 0xFFFFu));
      s += bf16_f32((unsigned short)(q[k] >> 16));
    }
  }
  red[tid] = s;
  __syncthreads();
  for (int off = 128; off > 0; off >>= 1) {
    if (tid < off) red[tid] += red[tid + off];
    __syncthreads();
  }
  if (tid == 0) out[0] = red[0];
}

// ---------------- launch ----------------
extern "C" void kernel_launch(void* const* d_in, const int* in_sizes, int n_in,
                              void* d_out, int out_size, void* d_ws, size_t ws_size,
                              hipStream_t stream) {
  const float* x = (const float*)d_in[0];     // [256][128][1024]
  const float* w_ih = (const float*)d_in[1];  // [2048][1024]
  const float* w_hh = (const float*)d_in[2];  // [2048][512]
  const float* b_ih = (const float*)d_in[3];  // [2048]
  const float* b_hh = (const float*)d_in[4];  // [2048]

  char* ws = (char*)d_ws;
  unsigned short* x_bf = (unsigned short*)(ws);                 // 67,108,864 B
  unsigned short* wih_bf = (unsigned short*)(ws + 67108864);    //  4,194,304 B
  unsigned short* whh_bf = (unsigned short*)(ws + 71303168);    //  2,097,152 B
  float* bias = (float*)(ws + 73400320);                        //      8,192 B
  unsigned* hring = (unsigned*)(ws + 73408512);                 //    524,288 B (4 slots)
  void* gx = (void*)(ws + 73932800);                            // Gx

  const size_t need_f32 = 73932800ull + (size_t)S_LEN * BATCH * G4 * 4;  // ~327 MB
  int gx_f32 = (ws_size >= need_f32) ? 1 : 0;

  // conversions + init
  cvt_bf16<<<(33554432 / 4 + 255) / 256, 256, 0, stream>>>(x, x_bf, 33554432);
  cvt_bf16<<<(2097152 / 4 + 255) / 256, 256, 0, stream>>>(w_ih, wih_bf, 2097152);
  cvt_bf16<<<(1048576 / 4 + 255) / 256, 256, 0, stream>>>(w_hh, whh_bf, 1048576);
  init_all<<<32, 256, 0, stream>>>(b_ih, b_hh, bias, hring);

  // big input GEMM (bias folded)
  if (gx_f32)
    gemm_bias<1><<<4096, 256, 0, stream>>>(x_bf, wih_bf, bias, gx);
  else
    gemm_bias<0><<<4096, 256, 0, stream>>>(x_bf, wih_bf, bias, gx);

  // persistent recurrence (co-residency via cooperative launch; sentinel sync)
  void* args[] = {(void*)&whh_bf, (void*)&gx, (void*)&gx_f32, (void*)&hring};
  hipLaunchCooperativeKernel((const void*)lstm_rec, dim3(128), dim3(256), args, 0, stream);

  // scalar output from ring slot 0
  reduce_sum<<<1, 256, 0, stream>>>((const unsigned short*)hring, (float*)d_out);
}

// Round 7
// 1274.846 us; speedup vs baseline: 3.1422x; 1.2214x over previous
//
#include <hip/hip_runtime.h>

typedef __attribute__((ext_vector_type(8))) short short8;
typedef __attribute__((ext_vector_type(4))) float f32x4;

// Problem constants
#define S_LEN 256
#define BATCH 128
#define IN_DIM 1024
#define HID 512
#define G4 2048  // 4*HID

#define SENT 0xFFFFFFFFu  // 2x bf16 NaN; h=o*tanh(c) can never be NaN

__device__ __forceinline__ unsigned short f32_bf16(float f) {
  unsigned int u = __float_as_uint(f);
  u = (u + 0x7FFFu + ((u >> 16) & 1u)) >> 16;  // RNE
  return (unsigned short)u;
}
__device__ __forceinline__ float bf16_f32(unsigned short h) {
  return __uint_as_float(((unsigned int)h) << 16);
}
__device__ __forceinline__ float sigm(float x) { return 1.0f / (1.0f + __expf(-x)); }
__device__ __forceinline__ float tanh_fast(float x) {
  return 1.0f - 2.0f / (__expf(2.0f * x) + 1.0f);
}

// ---------------- conversion kernels ----------------
__global__ void cvt_bf16(const float* __restrict__ src, unsigned short* __restrict__ dst, int n) {
  int i = (blockIdx.x * blockDim.x + threadIdx.x) * 4;
  if (i >= n) return;
  float4 v = *(const float4*)(src + i);
  ushort4 o;
  o.x = f32_bf16(v.x); o.y = f32_bf16(v.y); o.z = f32_bf16(v.z); o.w = f32_bf16(v.w);
  *(ushort4*)(dst + i) = o;
}

// bias fuse + ring init: slot0 = h(0) = 0 (valid), slots 1..256 = sentinel.
// 257-deep ring: every slot written exactly once by producers -> no resets, no ABA.
__global__ void init_all(const float* __restrict__ b_ih, const float* __restrict__ b_hh,
                         float* __restrict__ bias, uint4* __restrict__ hring4) {
  int i = blockIdx.x * blockDim.x + threadIdx.x;
  if (i < G4) bias[i] = b_ih[i] + b_hh[i];
  const int SLOT4 = BATCH * HID / 8;       // 8192 uint4 per slot
  const int TOT4 = 257 * SLOT4;            // 2,105,344 uint4
  const uint4 z = make_uint4(0u, 0u, 0u, 0u);
  const uint4 sN = make_uint4(SENT, SENT, SENT, SENT);
  for (int k = i; k < TOT4; k += gridDim.x * blockDim.x)
    hring4[k] = (k < SLOT4) ? z : sN;
}

// ---------------- GEMM: Gx = x_bf16 @ w_ih_bf16^T + bias ----------------
__device__ __forceinline__ void gl_lds16(const void* g, void* l) {
  __builtin_amdgcn_global_load_lds(
      (const __attribute__((address_space(1))) unsigned int*)g,
      (__attribute__((address_space(3))) unsigned int*)l, 16, 0, 0);
}

template <int C_F32>
__global__ __launch_bounds__(256) void gemm_bias(
    const unsigned short* __restrict__ A,   // [32768][1024] bf16
    const unsigned short* __restrict__ Bw,  // [2048][1024] bf16
    const float* __restrict__ bias,         // [2048]
    void* __restrict__ Cout) {              // [32768][2048] fp32 or bf16
  __shared__ __align__(16) unsigned short As[128 * 32];
  __shared__ __align__(16) unsigned short Bs[128 * 32];
  const int tid = threadIdx.x;
  const int w = tid >> 6, l = tid & 63;
  const int wm = w & 1, wn = w >> 1;
  const int nt = blockIdx.x & 15, mt = blockIdx.x >> 4;

  f32x4 acc[4][4];
#pragma unroll
  for (int i = 0; i < 4; i++)
#pragma unroll
    for (int j = 0; j < 4; j++) acc[i][j] = f32x4{0.f, 0.f, 0.f, 0.f};

  for (int k0 = 0; k0 < 1024; k0 += 32) {
    __syncthreads();
#pragma unroll
    for (int jj = 0; jj < 2; jj++) {
      int cid = (w * 2 + jj) * 64 + l;
      int row = cid >> 2, kc = cid & 3;
      const unsigned short* ga = A + (size_t)(mt * 128 + row) * 1024 + k0 + kc * 8;
      gl_lds16(ga, As + (w * 2 + jj) * 512);
      const unsigned short* gb = Bw + (size_t)(nt * 128 + row) * 1024 + k0 + kc * 8;
      gl_lds16(gb, Bs + (w * 2 + jj) * 512);
    }
    __syncthreads();
    short8 a[4], b[4];
#pragma unroll
    for (int i = 0; i < 4; i++)
      a[i] = *(const short8*)&As[(wm * 64 + i * 16 + (l & 15)) * 32 + (l >> 4) * 8];
#pragma unroll
    for (int j = 0; j < 4; j++)
      b[j] = *(const short8*)&Bs[(wn * 64 + j * 16 + (l & 15)) * 32 + (l >> 4) * 8];
#pragma unroll
    for (int i = 0; i < 4; i++)
#pragma unroll
      for (int j = 0; j < 4; j++)
        acc[i][j] = __builtin_amdgcn_mfma_f32_16x16x32_bf16(a[i], b[j], acc[i][j], 0, 0, 0);
  }
#pragma unroll
  for (int j = 0; j < 4; j++) {
    int cg = nt * 128 + wn * 64 + j * 16 + (l & 15);
    float bv = bias[cg];
#pragma unroll
    for (int i = 0; i < 4; i++) {
      int rbase = mt * 128 + wm * 64 + i * 16 + (l >> 4) * 4;
#pragma unroll
      for (int r = 0; r < 4; r++) {
        float v = acc[i][j][r] + bv;
        if (C_F32)
          ((float*)Cout)[(size_t)(rbase + r) * 2048 + cg] = v;
        else
          ((unsigned short*)Cout)[(size_t)(rbase + r) * 2048 + cg] = f32_bf16(v);
      }
    }
  }
}

// ---------------- persistent LSTM recurrence ----------------
// 8 independent groups (batch tiles m), 16 blocks each. h exchanged via a
// 257-deep sentinel-tagged LLC ring (write-once slots: no resets, no drains).
// Consumer: per-thread stripe retry — each thread's 8 qwords come from ONE
// producer block (kc=tid&127 -> s'=kc>>3), so straggler refetch is 1KB/round,
// threads of finished producers pass in one round. One barrier per step.
__global__ __launch_bounds__(256, 1) void lstm_rec(
    const unsigned short* __restrict__ whh,  // [2048][512] bf16
    const void* __restrict__ gx,             // [256][128][2048] fp32 or bf16 (bias folded)
    int gx_f32,
    unsigned* __restrict__ hring) {          // [257][128][512] bf16 ring
  __shared__ __align__(16) unsigned short Hs[2][16][520];  // double-buffered h tile
  __shared__ __align__(16) float Gt[16][132];              // wave-column-private

  const int tid = threadIdx.x;
  const int w = tid >> 6, l = tid & 63;
  const int m = blockIdx.x & 7;   // batch tile / group (round-robin XCD)
  const int s = blockIdx.x >> 3;  // hidden slice (16 slices of 32 cols)

  // ---- preload W_hh fragments (constant over t) ----
  short8 bw[16][2];
#pragma unroll
  for (int u = 0; u < 2; u++) {
    int n = (2 * w + u) * 16 + (l & 15);   // local gate-col n = j*4+g
    int jn = n >> 2, g = n & 3;
    int R = g * 512 + s * 32 + jn;         // global gate row
    const unsigned short* base = whh + (size_t)R * 512 + ((l >> 4) * 8);
#pragma unroll
    for (int kk = 0; kk < 16; kk++) bw[kk][u] = *(const short8*)(base + kk * 32);
  }

  // pointwise ownership: batch b = l&15, col pair p = 4w + (l>>4) (wave-aligned)
  const int b = l & 15;
  const int p = 4 * w + (l >> 4);
  const int gb = m * 16 + b;
  const int colg = s * 32 + 2 * p;
  float c0 = 0.f, c1 = 0.f;

  const float* gxf = (const float*)gx;
  const unsigned short* gxb = (const unsigned short*)gx;
  const int SLOTW = BATCH * HID / 2;  // uints per slot
  const unsigned long long* hull = (const unsigned long long*)hring;
  const int SLOTQ = BATCH * HID / 4;  // ulls per slot

  // staging: thread's 8 qwords = rows {it*2+(tid>>7)}, fixed kc = tid&127
  const int skc = tid & 127;
  const int srow = tid >> 7;

  for (int t = 0; t < S_LEN; t++) {
    // ---- gx prefetch (independent of h; overlaps the spin) ----
    float2 pg[4];
    {
      size_t base = (size_t)(t * BATCH + gb) * G4 + colg;
      if (gx_f32) {
#pragma unroll
        for (int g = 0; g < 4; g++) pg[g] = *(const float2*)(gxf + base + (size_t)g * 512);
      } else {
#pragma unroll
        for (int g = 0; g < 4; g++) {
          unsigned u = *(const unsigned*)(gxb + base + (size_t)g * 512);
          pg[g].x = bf16_f32((unsigned short)(u & 0xFFFFu));
          pg[g].y = bf16_f32((unsigned short)(u >> 16));
        }
      }
    }

    // ---- per-thread stripe load + retry (slot t; data load IS the sync) ----
    const unsigned long long* src = hull + (size_t)t * SLOTQ;
    unsigned long long v[8];
#pragma unroll
    for (int it = 0; it < 8; it++)
      v[it] = __hip_atomic_load(&src[(size_t)(m * 16 + it * 2 + srow) * 128 + skc],
                                __ATOMIC_RELAXED, __HIP_MEMORY_SCOPE_AGENT);
    for (;;) {
      int bad = 0;
#pragma unroll
      for (int it = 0; it < 8; it++)
        bad |= (((unsigned)v[it] == SENT) | ((unsigned)(v[it] >> 32) == SENT)) << it;
      if (!bad) break;
#pragma unroll
      for (int it = 0; it < 8; it++)
        if ((bad >> it) & 1)
          v[it] = __hip_atomic_load(&src[(size_t)(m * 16 + it * 2 + srow) * 128 + skc],
                                    __ATOMIC_RELAXED, __HIP_MEMORY_SCOPE_AGENT);
    }
    const int buf = t & 1;
#pragma unroll
    for (int it = 0; it < 8; it++)
      *(unsigned long long*)&Hs[buf][it * 2 + srow][skc * 4] = v[it];
    __syncthreads();

    // ---- gates tile via MFMA (LDS A-fragments, register B) ----
    f32x4 acc0 = f32x4{0.f, 0.f, 0.f, 0.f};
    f32x4 acc1 = f32x4{0.f, 0.f, 0.f, 0.f};
#pragma unroll
    for (int kk = 0; kk < 16; kk++) {
      short8 a = *(const short8*)&Hs[buf][l & 15][kk * 32 + (l >> 4) * 8];
      acc0 = __builtin_amdgcn_mfma_f32_16x16x32_bf16(a, bw[kk][0], acc0, 0, 0, 0);
      acc1 = __builtin_amdgcn_mfma_f32_16x16x32_bf16(a, bw[kk][1], acc1, 0, 0, 0);
    }

    // ---- Gt exchange (own-wave columns only; in-wave lgkmcnt suffices) ----
#pragma unroll
    for (int r = 0; r < 4; r++) {
      Gt[(l >> 4) * 4 + r][(2 * w + 0) * 16 + (l & 15)] = acc0[r];
      Gt[(l >> 4) * 4 + r][(2 * w + 1) * 16 + (l & 15)] = acc1[r];
    }

    // ---- pointwise: batch b, cols colg / colg+1 ----
    float4 g0 = *(const float4*)&Gt[b][8 * p];
    float4 g1 = *(const float4*)&Gt[b][8 * p + 4];
    float i0 = sigm(g0.x + pg[0].x), f0 = sigm(g0.y + pg[1].x);
    float gg0 = tanh_fast(g0.z + pg[2].x), o0 = sigm(g0.w + pg[3].x);
    c0 = f0 * c0 + i0 * gg0;
    float h0 = o0 * tanh_fast(c0);
    float i1 = sigm(g1.x + pg[0].y), f1 = sigm(g1.y + pg[1].y);
    float gg1 = tanh_fast(g1.z + pg[2].y), o1 = sigm(g1.w + pg[3].y);
    c1 = f1 * c1 + i1 * gg1;
    float h1 = o1 * tanh_fast(c1);
    unsigned hp = (unsigned)f32_bf16(h0) | ((unsigned)f32_bf16(h1) << 16);

    // ---- store h(t+1) into virgin slot t+1: this IS the producer sync ----
    __hip_atomic_store(&hring[(size_t)(t + 1) * SLOTW + gb * 256 + s * 16 + p], hp,
                       __ATOMIC_RELAXED, __HIP_MEMORY_SCOPE_AGENT);
  }
  // final h(256) is in slot 256
}

// ---------------- final reduction: sum over h [128][512] ----------------
__global__ void reduce_sum(const unsigned short* __restrict__ h, float* __restrict__ out) {
  __shared__ float red[256];
  int tid = threadIdx.x;
  float s = 0.f;
  for (int i = tid * 8; i < BATCH * HID; i += 256 * 8) {
    uint4 v = *(const uint4*)(h + i);
    unsigned int q[4] = {v.x, v.y, v.z, v.w};
#pragma unroll
    for (int k = 0; k < 4; k++) {
      s += bf16_f32((unsigned short)(q[k] & 0xFFFFu));
      s += bf16_f32((unsigned short)(q[k] >> 16));
    }
  }
  red[tid] = s;
  __syncthreads();
  for (int off = 128; off > 0; off >>= 1) {
    if (tid < off) red[tid] += red[tid + off];
    __syncthreads();
  }
  if (tid == 0) out[0] = red[0];
}

// ---------------- launch ----------------
extern "C" void kernel_launch(void* const* d_in, const int* in_sizes, int n_in,
                              void* d_out, int out_size, void* d_ws, size_t ws_size,
                              hipStream_t stream) {
  const float* x = (const float*)d_in[0];     // [256][128][1024]
  const float* w_ih = (const float*)d_in[1];  // [2048][1024]
  const float* w_hh = (const float*)d_in[2];  // [2048][512]
  const float* b_ih = (const float*)d_in[3];  // [2048]
  const float* b_hh = (const float*)d_in[4];  // [2048]

  char* ws = (char*)d_ws;
  unsigned short* x_bf = (unsigned short*)(ws);                 // 67,108,864 B
  unsigned short* wih_bf = (unsigned short*)(ws + 67108864);    //  4,194,304 B
  unsigned short* whh_bf = (unsigned short*)(ws + 71303168);    //  2,097,152 B
  float* bias = (float*)(ws + 73400320);                        //      8,192 B
  unsigned* hring = (unsigned*)(ws + 73408512);                 // 33,685,504 B (257 slots)
  void* gx = (void*)(ws + 107094016);                           // Gx

  const size_t need_f32 = 107094016ull + (size_t)S_LEN * BATCH * G4 * 4;  // ~358 MB
  int gx_f32 = (ws_size >= need_f32) ? 1 : 0;

  // conversions + init (poison ring once; ~34 MB, off recurrence critical path)
  cvt_bf16<<<(33554432 / 4 + 255) / 256, 256, 0, stream>>>(x, x_bf, 33554432);
  cvt_bf16<<<(2097152 / 4 + 255) / 256, 256, 0, stream>>>(w_ih, wih_bf, 2097152);
  cvt_bf16<<<(1048576 / 4 + 255) / 256, 256, 0, stream>>>(w_hh, whh_bf, 1048576);
  init_all<<<256, 256, 0, stream>>>(b_ih, b_hh, bias, (uint4*)hring);

  // big input GEMM (bias folded)
  if (gx_f32)
    gemm_bias<1><<<4096, 256, 0, stream>>>(x_bf, wih_bf, bias, gx);
  else
    gemm_bias<0><<<4096, 256, 0, stream>>>(x_bf, wih_bf, bias, gx);

  // persistent recurrence (co-residency via cooperative launch; sentinel-ring sync)
  void* args[] = {(void*)&whh_bf, (void*)&gx, (void*)&gx_f32, (void*)&hring};
  hipLaunchCooperativeKernel((const void*)lstm_rec, dim3(128), dim3(256), args, 0, stream);

  // scalar output from ring slot 256
  reduce_sum<<<1, 256, 0, stream>>>((const unsigned short*)(hring + 256 * (BATCH * HID / 2)),
                                    (float*)d_out);
}

// Round 8
// 1204.410 us; speedup vs baseline: 3.3259x; 1.0585x over previous
//
#include <hip/hip_runtime.h>

typedef __attribute__((ext_vector_type(8))) short short8;
typedef __attribute__((ext_vector_type(4))) float f32x4;

// Problem constants
#define S_LEN 256
#define BATCH 128
#define IN_DIM 1024
#define HID 512
#define G4 2048  // 4*HID

#define SENT 0xFFFFFFFFu  // 2x bf16 NaN; h=o*tanh(c) can never be NaN

__device__ __forceinline__ unsigned short f32_bf16(float f) {
  unsigned int u = __float_as_uint(f);
  u = (u + 0x7FFFu + ((u >> 16) & 1u)) >> 16;  // RNE
  return (unsigned short)u;
}
__device__ __forceinline__ float bf16_f32(unsigned short h) {
  return __uint_as_float(((unsigned int)h) << 16);
}
__device__ __forceinline__ float sigm(float x) { return 1.0f / (1.0f + __expf(-x)); }
__device__ __forceinline__ float tanh_fast(float x) {
  return 1.0f - 2.0f / (__expf(2.0f * x) + 1.0f);
}

// ---------------- conversion kernels ----------------
__global__ void cvt_bf16(const float* __restrict__ src, unsigned short* __restrict__ dst, int n) {
  int i = (blockIdx.x * blockDim.x + threadIdx.x) * 4;
  if (i >= n) return;
  float4 v = *(const float4*)(src + i);
  ushort4 o;
  o.x = f32_bf16(v.x); o.y = f32_bf16(v.y); o.z = f32_bf16(v.z); o.w = f32_bf16(v.w);
  *(ushort4*)(dst + i) = o;
}

// bias fuse + ring init: slot0 = h(0) = 0 (valid), slots 1..256 = sentinel.
// 257-deep ring: every slot written exactly once by producers -> no resets, no ABA.
__global__ void init_all(const float* __restrict__ b_ih, const float* __restrict__ b_hh,
                         float* __restrict__ bias, uint4* __restrict__ hring4) {
  int i = blockIdx.x * blockDim.x + threadIdx.x;
  if (i < G4) bias[i] = b_ih[i] + b_hh[i];
  const int SLOT4 = BATCH * HID / 8;       // 8192 uint4 per slot
  const int TOT4 = 257 * SLOT4;            // 2,105,344 uint4
  const uint4 z = make_uint4(0u, 0u, 0u, 0u);
  const uint4 sN = make_uint4(SENT, SENT, SENT, SENT);
  for (int k = i; k < TOT4; k += gridDim.x * blockDim.x)
    hring4[k] = (k < SLOT4) ? z : sN;
}

// ---------------- GEMM: Gx = x_bf16 @ w_ih_bf16^T + bias ----------------
__device__ __forceinline__ void gl_lds16(const void* g, void* l) {
  __builtin_amdgcn_global_load_lds(
      (const __attribute__((address_space(1))) unsigned int*)g,
      (__attribute__((address_space(3))) unsigned int*)l, 16, 0, 0);
}

template <int C_F32>
__global__ __launch_bounds__(256) void gemm_bias(
    const unsigned short* __restrict__ A,   // [32768][1024] bf16
    const unsigned short* __restrict__ Bw,  // [2048][1024] bf16
    const float* __restrict__ bias,         // [2048]
    void* __restrict__ Cout) {              // [32768][2048] fp32 or bf16
  __shared__ __align__(16) unsigned short As[128 * 32];
  __shared__ __align__(16) unsigned short Bs[128 * 32];
  const int tid = threadIdx.x;
  const int w = tid >> 6, l = tid & 63;
  const int wm = w & 1, wn = w >> 1;
  const int nt = blockIdx.x & 15, mt = blockIdx.x >> 4;

  f32x4 acc[4][4];
#pragma unroll
  for (int i = 0; i < 4; i++)
#pragma unroll
    for (int j = 0; j < 4; j++) acc[i][j] = f32x4{0.f, 0.f, 0.f, 0.f};

  for (int k0 = 0; k0 < 1024; k0 += 32) {
    __syncthreads();
#pragma unroll
    for (int jj = 0; jj < 2; jj++) {
      int cid = (w * 2 + jj) * 64 + l;
      int row = cid >> 2, kc = cid & 3;
      const unsigned short* ga = A + (size_t)(mt * 128 + row) * 1024 + k0 + kc * 8;
      gl_lds16(ga, As + (w * 2 + jj) * 512);
      const unsigned short* gb = Bw + (size_t)(nt * 128 + row) * 1024 + k0 + kc * 8;
      gl_lds16(gb, Bs + (w * 2 + jj) * 512);
    }
    __syncthreads();
    short8 a[4], b[4];
#pragma unroll
    for (int i = 0; i < 4; i++)
      a[i] = *(const short8*)&As[(wm * 64 + i * 16 + (l & 15)) * 32 + (l >> 4) * 8];
#pragma unroll
    for (int j = 0; j < 4; j++)
      b[j] = *(const short8*)&Bs[(wn * 64 + j * 16 + (l & 15)) * 32 + (l >> 4) * 8];
#pragma unroll
    for (int i = 0; i < 4; i++)
#pragma unroll
      for (int j = 0; j < 4; j++)
        acc[i][j] = __builtin_amdgcn_mfma_f32_16x16x32_bf16(a[i], b[j], acc[i][j], 0, 0, 0);
  }
#pragma unroll
  for (int j = 0; j < 4; j++) {
    int cg = nt * 128 + wn * 64 + j * 16 + (l & 15);
    float bv = bias[cg];
#pragma unroll
    for (int i = 0; i < 4; i++) {
      int rbase = mt * 128 + wm * 64 + i * 16 + (l >> 4) * 4;
#pragma unroll
      for (int r = 0; r < 4; r++) {
        float v = acc[i][j][r] + bv;
        if (C_F32)
          ((float*)Cout)[(size_t)(rbase + r) * 2048 + cg] = v;
        else
          ((unsigned short*)Cout)[(size_t)(rbase + r) * 2048 + cg] = f32_bf16(v);
      }
    }
  }
}

// ---------------- persistent LSTM recurrence ----------------
// 8 groups (batch tiles m) x 16 blocks. 257-deep sentinel LLC ring (write-once).
// R8: (1) speculative prefetch of next stripe+gx during compute — hides one RTT;
// (2) self-stripe bypass — each block's own 32 cols enter the next Hs buffer
// via LDS at pointwise time, skipping the LLC round trip entirely.
__global__ __launch_bounds__(256, 1) void lstm_rec(
    const unsigned short* __restrict__ whh,  // [2048][512] bf16
    const void* __restrict__ gx,             // [256][128][2048] fp32 or bf16 (bias folded)
    int gx_f32,
    unsigned* __restrict__ hring) {          // [257][128][512] bf16 ring
  __shared__ __align__(16) unsigned short Hs[2][16][520];  // double-buffered h tile
  __shared__ __align__(16) float Gt[16][132];              // wave-column-private

  const int tid = threadIdx.x;
  const int w = tid >> 6, l = tid & 63;
  const int m = blockIdx.x & 7;   // batch tile / group
  const int s = blockIdx.x >> 3;  // hidden slice (16 slices of 32 cols)

  // ---- preload W_hh fragments (constant over t) ----
  short8 bw[16][2];
#pragma unroll
  for (int u = 0; u < 2; u++) {
    int n = (2 * w + u) * 16 + (l & 15);   // local gate-col n = j*4+g
    int jn = n >> 2, g = n & 3;
    int R = g * 512 + s * 32 + jn;         // global gate row
    const unsigned short* base = whh + (size_t)R * 512 + ((l >> 4) * 8);
#pragma unroll
    for (int kk = 0; kk < 16; kk++) bw[kk][u] = *(const short8*)(base + kk * 32);
  }

  // pointwise ownership: batch b = l&15, col pair p = 4w + (l>>4) (wave-aligned)
  const int b = l & 15;
  const int p = 4 * w + (l >> 4);
  const int gb = m * 16 + b;
  const int colg = s * 32 + 2 * p;
  float c0 = 0.f, c1 = 0.f;

  const float* gxf = (const float*)gx;
  const unsigned short* gxb = (const unsigned short*)gx;
  const int SLOTW = BATCH * HID / 2;  // uints per slot
  const unsigned long long* hull = (const unsigned long long*)hring;
  const int SLOTQ = BATCH * HID / 4;  // ulls per slot

  // staging: thread's 8 qwords = rows {it*2+srow}, fixed kc = tid&127
  const int skc = tid & 127;
  const int srow = tid >> 7;
  // stripe producer block s' = (tid>>3)&15; self-stripe = comes from our own block
  const bool selfst = (((tid >> 3) & 15) == s);

  // ---- initial loads for t=0 (slot 0 valid; gx row 0) ----
  unsigned long long v[8];
#pragma unroll
  for (int it = 0; it < 8; it++)
    v[it] = __hip_atomic_load(&hull[(size_t)(m * 16 + it * 2 + srow) * 128 + skc],
                              __ATOMIC_RELAXED, __HIP_MEMORY_SCOPE_AGENT);
  float2 pg[4];
  {
    size_t base0 = (size_t)gb * G4 + colg;
    if (gx_f32) {
#pragma unroll
      for (int g = 0; g < 4; g++) pg[g] = *(const float2*)(gxf + base0 + (size_t)g * 512);
    } else {
#pragma unroll
      for (int g = 0; g < 4; g++) {
        unsigned u = *(const unsigned*)(gxb + base0 + (size_t)g * 512);
        pg[g].x = bf16_f32((unsigned short)(u & 0xFFFFu));
        pg[g].y = bf16_f32((unsigned short)(u >> 16));
      }
    }
  }

  for (int t = 0; t < S_LEN; t++) {
    const int buf = t & 1;
    const unsigned long long* src = hull + (size_t)t * SLOTQ;

    // ---- finalize stripe: reload only sentinel lanes (skip self-stripe at t>0) ----
    if (!(selfst && t > 0)) {
      for (;;) {
        int bad = 0;
#pragma unroll
        for (int it = 0; it < 8; it++)
          bad |= (((unsigned)v[it] == SENT) | ((unsigned)(v[it] >> 32) == SENT)) << it;
        if (!bad) break;
#pragma unroll
        for (int it = 0; it < 8; it++)
          if ((bad >> it) & 1)
            v[it] = __hip_atomic_load(&src[(size_t)(m * 16 + it * 2 + srow) * 128 + skc],
                                      __ATOMIC_RELAXED, __HIP_MEMORY_SCOPE_AGENT);
      }
#pragma unroll
      for (int it = 0; it < 8; it++)
        *(unsigned long long*)&Hs[buf][it * 2 + srow][skc * 4] = v[it];
    }
    __syncthreads();

    // ---- speculative prefetch for t+1: stripe (non-self) + gx; flies under compute ----
    unsigned long long vn[8];
    float2 pgn[4];
    if (t + 1 < S_LEN) {
      if (!selfst) {
        const unsigned long long* srcn = hull + (size_t)(t + 1) * SLOTQ;
#pragma unroll
        for (int it = 0; it < 8; it++)
          vn[it] = __hip_atomic_load(&srcn[(size_t)(m * 16 + it * 2 + srow) * 128 + skc],
                                     __ATOMIC_RELAXED, __HIP_MEMORY_SCOPE_AGENT);
      }
      size_t basen = (size_t)((t + 1) * BATCH + gb) * G4 + colg;
      if (gx_f32) {
#pragma unroll
        for (int g = 0; g < 4; g++) pgn[g] = *(const float2*)(gxf + basen + (size_t)g * 512);
      } else {
#pragma unroll
        for (int g = 0; g < 4; g++) {
          unsigned u = *(const unsigned*)(gxb + basen + (size_t)g * 512);
          pgn[g].x = bf16_f32((unsigned short)(u & 0xFFFFu));
          pgn[g].y = bf16_f32((unsigned short)(u >> 16));
        }
      }
    }

    // ---- gates tile via MFMA (LDS A-fragments, register B) ----
    f32x4 acc0 = f32x4{0.f, 0.f, 0.f, 0.f};
    f32x4 acc1 = f32x4{0.f, 0.f, 0.f, 0.f};
#pragma unroll
    for (int kk = 0; kk < 16; kk++) {
      short8 a = *(const short8*)&Hs[buf][l & 15][kk * 32 + (l >> 4) * 8];
      acc0 = __builtin_amdgcn_mfma_f32_16x16x32_bf16(a, bw[kk][0], acc0, 0, 0, 0);
      acc1 = __builtin_amdgcn_mfma_f32_16x16x32_bf16(a, bw[kk][1], acc1, 0, 0, 0);
    }

    // ---- Gt exchange (own-wave columns only; in-wave lgkmcnt suffices) ----
#pragma unroll
    for (int r = 0; r < 4; r++) {
      Gt[(l >> 4) * 4 + r][(2 * w + 0) * 16 + (l & 15)] = acc0[r];
      Gt[(l >> 4) * 4 + r][(2 * w + 1) * 16 + (l & 15)] = acc1[r];
    }

    // ---- pointwise: batch b, cols colg / colg+1 ----
    float4 g0 = *(const float4*)&Gt[b][8 * p];
    float4 g1 = *(const float4*)&Gt[b][8 * p + 4];
    float i0 = sigm(g0.x + pg[0].x), f0 = sigm(g0.y + pg[1].x);
    float gg0 = tanh_fast(g0.z + pg[2].x), o0 = sigm(g0.w + pg[3].x);
    c0 = f0 * c0 + i0 * gg0;
    float h0 = o0 * tanh_fast(c0);
    float i1 = sigm(g1.x + pg[0].y), f1 = sigm(g1.y + pg[1].y);
    float gg1 = tanh_fast(g1.z + pg[2].y), o1 = sigm(g1.w + pg[3].y);
    c1 = f1 * c1 + i1 * gg1;
    float h1 = o1 * tanh_fast(c1);
    unsigned hp = (unsigned)f32_bf16(h0) | ((unsigned)f32_bf16(h1) << 16);

    // ---- publish h(t+1): ring (for other blocks) + next Hs buffer (self cols) ----
    __hip_atomic_store(&hring[(size_t)(t + 1) * SLOTW + gb * 256 + s * 16 + p], hp,
                       __ATOMIC_RELAXED, __HIP_MEMORY_SCOPE_AGENT);
    *(unsigned*)&Hs[buf ^ 1][b][colg] = hp;  // self-stripe bypass

    // rotate prefetched state
#pragma unroll
    for (int it = 0; it < 8; it++) v[it] = vn[it];
#pragma unroll
    for (int g = 0; g < 4; g++) pg[g] = pgn[g];
  }
  // final h(256) is in slot 256
}

// ---------------- final reduction: sum over h [128][512] ----------------
__global__ void reduce_sum(const unsigned short* __restrict__ h, float* __restrict__ out) {
  __shared__ float red[256];
  int tid = threadIdx.x;
  float s = 0.f;
  for (int i = tid * 8; i < BATCH * HID; i += 256 * 8) {
    uint4 v = *(const uint4*)(h + i);
    unsigned int q[4] = {v.x, v.y, v.z, v.w};
#pragma unroll
    for (int k = 0; k < 4; k++) {
      s += bf16_f32((unsigned short)(q[k] & 0xFFFFu));
      s += bf16_f32((unsigned short)(q[k] >> 16));
    }
  }
  red[tid] = s;
  __syncthreads();
  for (int off = 128; off > 0; off >>= 1) {
    if (tid < off) red[tid] += red[tid + off];
    __syncthreads();
  }
  if (tid == 0) out[0] = red[0];
}

// ---------------- launch ----------------
extern "C" void kernel_launch(void* const* d_in, const int* in_sizes, int n_in,
                              void* d_out, int out_size, void* d_ws, size_t ws_size,
                              hipStream_t stream) {
  const float* x = (const float*)d_in[0];     // [256][128][1024]
  const float* w_ih = (const float*)d_in[1];  // [2048][1024]
  const float* w_hh = (const float*)d_in[2];  // [2048][512]
  const float* b_ih = (const float*)d_in[3];  // [2048]
  const float* b_hh = (const float*)d_in[4];  // [2048]

  char* ws = (char*)d_ws;
  unsigned short* x_bf = (unsigned short*)(ws);                 // 67,108,864 B
  unsigned short* wih_bf = (unsigned short*)(ws + 67108864);    //  4,194,304 B
  unsigned short* whh_bf = (unsigned short*)(ws + 71303168);    //  2,097,152 B
  float* bias = (float*)(ws + 73400320);                        //      8,192 B
  unsigned* hring = (unsigned*)(ws + 73408512);                 // 33,685,504 B (257 slots)
  void* gx = (void*)(ws + 107094016);                           // Gx

  const size_t need_f32 = 107094016ull + (size_t)S_LEN * BATCH * G4 * 4;  // ~358 MB
  int gx_f32 = (ws_size >= need_f32) ? 1 : 0;

  // conversions + init (poison ring once; off recurrence critical path)
  cvt_bf16<<<(33554432 / 4 + 255) / 256, 256, 0, stream>>>(x, x_bf, 33554432);
  cvt_bf16<<<(2097152 / 4 + 255) / 256, 256, 0, stream>>>(w_ih, wih_bf, 2097152);
  cvt_bf16<<<(1048576 / 4 + 255) / 256, 256, 0, stream>>>(w_hh, whh_bf, 1048576);
  init_all<<<256, 256, 0, stream>>>(b_ih, b_hh, bias, (uint4*)hring);

  // big input GEMM (bias folded)
  if (gx_f32)
    gemm_bias<1><<<4096, 256, 0, stream>>>(x_bf, wih_bf, bias, gx);
  else
    gemm_bias<0><<<4096, 256, 0, stream>>>(x_bf, wih_bf, bias, gx);

  // persistent recurrence (co-residency via cooperative launch; sentinel-ring sync)
  void* args[] = {(void*)&whh_bf, (void*)&gx, (void*)&gx_f32, (void*)&hring};
  hipLaunchCooperativeKernel((const void*)lstm_rec, dim3(128), dim3(256), args, 0, stream);

  // scalar output from ring slot 256
  reduce_sum<<<1, 256, 0, stream>>>((const unsigned short*)(hring + 256 * (BATCH * HID / 2)),
                                    (float*)d_out);
}